// Round 19
// baseline (281.752 us; speedup 1.0000x reference)
//
#include <hip/hip_runtime.h>
#include <hip/hip_bf16.h>

// B=128, N=50, NB=32, K=8, H=64, D=512. sites=6400, neighbor rows=204800.
// Fused: per block, 64 neighbor rows (=2 sites) GEMM (bf16 MFMA) into LDS zbuf
// (f16), then 3 routing iterations in-block, write fp32 out.
// This round: 512 threads / 8 waves per block (wave = 64 rows x 64 cols,
// acc 64 VGPR) -> 16 waves/CU at the same 80 KB LDS / 2 blocks/CU. Identical
// traffic, double the latency-hiding TLP. Ledger: 5 DMAs/wave/step uniform,
// vmcnt(5) aligned to whole stages (r8-verified pattern).

#define D_DIM 512
#define BM 64
#define BK 32
#define KSTEPS 16

typedef __attribute__((ext_vector_type(8))) short short8;
typedef __attribute__((ext_vector_type(4))) float f32x4;
typedef _Float16 fp16_t;
typedef __attribute__((ext_vector_type(2))) _Float16 h2v;
typedef __attribute__((ext_vector_type(4))) _Float16 h4v;
typedef __attribute__((ext_vector_type(8))) _Float16 h8v;

static __device__ __forceinline__ short f2bf(float f) {
    __bf16 b = (__bf16)f;
    return __builtin_bit_cast(short, b);
}
static __device__ __forceinline__ void gload_lds16(const void* g, void* l) {
    __builtin_amdgcn_global_load_lds(
        (const __attribute__((address_space(1))) void*)g,
        (__attribute__((address_space(3))) void*)l, 16, 0, 0);
}

#if __has_builtin(__builtin_amdgcn_fdot2)
static __device__ __forceinline__ float fdot2(h2v a, h2v b, float c) {
    return __builtin_amdgcn_fdot2(a, b, c, false);
}
#else
static __device__ __forceinline__ float fdot2(h2v a, h2v b, float c) {
    return fmaf((float)a[0], (float)b[0], fmaf((float)a[1], (float)b[1], c));
}
#endif

__global__ __launch_bounds__(256) void wconv(const float* __restrict__ W,
                                             short* __restrict__ Wb) {
    const int i = (blockIdx.x * 256 + threadIdx.x) * 8;
    const float4 v0 = *reinterpret_cast<const float4*>(W + i);
    const float4 v1 = *reinterpret_cast<const float4*>(W + i + 4);
    short8 o;
    o[0] = f2bf(v0.x); o[1] = f2bf(v0.y); o[2] = f2bf(v0.z); o[3] = f2bf(v0.w);
    o[4] = f2bf(v1.x); o[5] = f2bf(v1.y); o[6] = f2bf(v1.z); o[7] = f2bf(v1.w);
    *reinterpret_cast<short8*>(Wb + i) = o;
}

// 512 threads = 8 waves; wave w -> 64 rows x cols [64w, 64w+64).
// lAf32[2]: [64][32] f32 (8 KB each); lB[2]: [512][32] bf16 (32 KB each).
template <bool FUSED>
__global__ __launch_bounds__(512, 4) void gemm_route(
    const float* __restrict__ A,     // [R,512] fp32
    const short* __restrict__ Wb,    // [512,512] bf16
    const float* __restrict__ bias,  // [512]
    fp16_t* __restrict__ Zs,         // !FUSED: s output f16
    const fp16_t* __restrict__ S,    // FUSED: s input f16
    const int* __restrict__ miter_ptr,
    float* __restrict__ out)         // FUSED: [sites,512] fp32
{
    __shared__ __align__(16) char smem[81920];
    float* const lAf32 = (float*)smem;           // [2][2048] f32  (16 KB)
    short* const lB = (short*)(smem + 16384);    // [2][16384] bf16 (64 KB)

    const int t = threadIdx.x;
    const int lane = t & 63;
    const int wid = t >> 6;                      // 0..7
    const size_t row0 = (size_t)blockIdx.x * BM;
    const int wc = wid * 64;
    const int l15 = lane & 15;
    const int q = lane >> 4;

    const int cb = wc + l15;
    float bcol[4];
    #pragma unroll
    for (int n = 0; n < 4; ++n) bcol[n] = bias[cb + n * 16];
    int miter = 0;
    if (FUSED) miter = *miter_ptr;

    // 5 DMAs per wave per step: 4 B-chunks + 1 A-chunk (1024 B each).
    auto stage = [&](int step, int buf) {
        const int k0 = (step < KSTEPS ? step : 0) * BK;
        #pragma unroll
        for (int i = 0; i < 4; ++i) {            // B: chunk = 16 rows x 64 B
            const int c = wid * 4 + i;           // 0..31
            const int r = c * 16 + (lane >> 2);
            const int g = ((lane & 3) - (r >> 1)) & 3;
            gload_lds16(Wb + (size_t)r * D_DIM + k0 + g * 8,
                        lB + buf * 16384 + c * 512);
        }
        {                                        // A: chunk = 8 rows x 128 B
            const int c = wid;                   // 0..7
            const int r = c * 8 + (lane >> 3);
            const int g = ((lane & 7) - 2 * (r & 3)) & 7;
            gload_lds16(A + (row0 + r) * D_DIM + k0 + g * 4,
                        lAf32 + buf * 2048 + c * 256);
        }
    };

    f32x4 acc[4][4] = {};
    auto compute = [&](int buf) {
        short8 af[4], bfr[4];
        #pragma unroll
        for (int m = 0; m < 4; ++m) {
            const int r = m * 16 + l15;
            const float* ap = lAf32 + buf * 2048 + r * 32 + ((q + (r & 3)) & 3) * 8;
            const f32x4 a0 = *reinterpret_cast<const f32x4*>(ap);
            const f32x4 a1 = *reinterpret_cast<const f32x4*>(ap + 4);
            short8 f;
            f[0] = f2bf(a0[0]); f[1] = f2bf(a0[1]);
            f[2] = f2bf(a0[2]); f[3] = f2bf(a0[3]);
            f[4] = f2bf(a1[0]); f[5] = f2bf(a1[1]);
            f[6] = f2bf(a1[2]); f[7] = f2bf(a1[3]);
            af[m] = f;
        }
        #pragma unroll
        for (int n = 0; n < 4; ++n) {
            const int r = wc + n * 16 + l15;
            bfr[n] = *reinterpret_cast<const short8*>(
                lB + buf * 16384 + r * 32 + ((q + (r >> 1)) & 3) * 8);
        }
        #pragma unroll
        for (int m = 0; m < 4; ++m)
            #pragma unroll
            for (int n = 0; n < 4; ++n)
                acc[m][n] = __builtin_amdgcn_mfma_f32_16x16x32_bf16(
                    af[m], bfr[n], acc[m][n], 0, 0, 0);
    };

    // ---- pipeline: counted vmcnt aligned to whole stages (r8 pattern)
    stage(0, 0);
    stage(1, 1);
    asm volatile("s_waitcnt vmcnt(5)" ::: "memory");    // stage0 (+scalars) done
    __builtin_amdgcn_s_barrier();
    #pragma unroll
    for (int tk = 0; tk < KSTEPS; ++tk) {
        compute(tk & 1);
        asm volatile("s_waitcnt lgkmcnt(0)" ::: "memory");  // reads consumed
        __builtin_amdgcn_s_barrier();                       // buf tk&1 free
        stage(tk + 2, tk & 1);                              // overwrite it
        asm volatile("s_waitcnt vmcnt(5)" ::: "memory");    // stage(tk+1) done
        __builtin_amdgcn_s_barrier();                       // visible to all
    }
    asm volatile("s_waitcnt vmcnt(0)" ::: "memory");        // drain tail junk
    __builtin_amdgcn_s_barrier();

    // ---- epilogue: bias + ReLU + l2norm (wave's 64 cols = one group); z f16.
    // FUSED also accumulates the per-site column sum (routing iteration 0).
    fp16_t* const zbuf = (fp16_t*)(smem + 16384);   // aliases lB (free now)
    float* const csum = (float*)(smem + 6144);      // [2][512] f32 (4 KB)
    float cs[2][4] = {};
    #pragma unroll
    for (int m = 0; m < 4; ++m) {
        #pragma unroll
        for (int r = 0; r < 4; ++r) {
            float v[4];
            float ss = 0.0f;
            #pragma unroll
            for (int n = 0; n < 4; ++n) {
                v[n] = fmaxf(acc[m][n][r] + bcol[n], 0.0f);
                ss = fmaf(v[n], v[n], ss);
            }
            ss += __shfl_xor(ss, 1);
            ss += __shfl_xor(ss, 2);
            ss += __shfl_xor(ss, 4);
            ss += __shfl_xor(ss, 8);
            const float inv = 1.0f / fmaxf(sqrtf(ss), 1e-12f);
            const int orow = m * 16 + q * 4 + r;   // 0..63
            if (FUSED) {
                const int st = m >> 1;             // rows 0-31 site0, 32-63 site1
                #pragma unroll
                for (int n = 0; n < 4; ++n) {
                    const float zv = v[n] * inv;
                    cs[st][n] += zv;
                    zbuf[orow * D_DIM + cb + n * 16] = (fp16_t)zv;
                }
            } else {
                #pragma unroll
                for (int n = 0; n < 4; ++n)
                    Zs[(row0 + orow) * D_DIM + cb + n * 16] = (fp16_t)(v[n] * inv);
            }
        }
    }

    if (!FUSED) return;

    // finish colsum: reduce over the 4 q-lane groups
    #pragma unroll
    for (int st = 0; st < 2; ++st)
        #pragma unroll
        for (int n = 0; n < 4; ++n) {
            cs[st][n] += __shfl_xor(cs[st][n], 16);
            cs[st][n] += __shfl_xor(cs[st][n], 32);
        }
    if (q == 0) {
        #pragma unroll
        for (int st = 0; st < 2; ++st)
            #pragma unroll
            for (int n = 0; n < 4; ++n)
                csum[st * D_DIM + cb + n * 16] = cs[st][n];
    }
    __syncthreads();   // zbuf + csum complete

    // ---- routing: 2 sites; threads 256-511 duplicate 0-255 (benign).
    fp16_t* const uh = (fp16_t*)smem;               // [2][512] f16
    float* const ppb = (float*)(smem + 4096);       // [2][256] f32
    const int tt = t & 127;
    const int ssid = (t >> 7) & 1;
    const size_t site = (size_t)blockIdx.x * 2 + ssid;
    fp16_t* const u_ = uh + ssid * D_DIM;
    float* const p_ = ppb + ssid * 256;
    const fp16_t* const zr = zbuf + ssid * 32 * D_DIM;

    const int e = tt * 4;
    const int go = tt >> 4;                  // capsule group of owned elems
    const h4v sv = *reinterpret_cast<const h4v*>(S + site * D_DIM + e);
    const float s0 = (float)sv[0], s1 = (float)sv[1];
    const float s2 = (float)sv[2], s3 = (float)sv[3];

    // iteration 0 from precomputed colsum: u = s + 0.125 * csum
    const float4 cv = *reinterpret_cast<const float4*>(csum + ssid * D_DIM + e);
    float v0 = fmaf(cv.x, 0.125f, s0);
    float v1 = fmaf(cv.y, 0.125f, s1);
    float v2 = fmaf(cv.z, 0.125f, s2);
    float v3 = fmaf(cv.w, 0.125f, s3);

    const int dm = tt >> 2;                  // neighbor for this thread's dots
    const int ka = (tt & 3) * 2;             // capsule pair
    const fp16_t* const za = zr + dm * D_DIM + ka * 64;
    const fp16_t* const ua = u_ + ka * 64;

    for (int it = 1; it < miter; ++it) {
        // normalize u per 64-group (16-thread shfl groups, wave-aligned)
        float ssum = v0 * v0 + v1 * v1 + v2 * v2 + v3 * v3;
        ssum += __shfl_xor(ssum, 1);
        ssum += __shfl_xor(ssum, 2);
        ssum += __shfl_xor(ssum, 4);
        ssum += __shfl_xor(ssum, 8);
        const float inv = 1.0f / fmaxf(sqrtf(ssum), 1e-12f);
        v0 *= inv; v1 *= inv; v2 *= inv; v3 *= inv;
        h4v uw; uw[0] = (fp16_t)v0; uw[1] = (fp16_t)v1;
        uw[2] = (fp16_t)v2; uw[3] = (fp16_t)v3;
        *reinterpret_cast<h4v*>(u_ + e) = uw;
        __syncthreads();

        // dots p[dm][ka], p[dm][ka+1] via v_dot2_f32_f16; staggered octets
        float da = 0.0f, db = 0.0f;
        #pragma unroll
        for (int j = 0; j < 8; ++j) {
            const int jj = ((j + (tt & 7)) & 7) * 8;
            const h8v zA = *reinterpret_cast<const h8v*>(za + jj);
            const h8v uA = *reinterpret_cast<const h8v*>(ua + jj);
            const h8v zB = *reinterpret_cast<const h8v*>(za + 64 + jj);
            const h8v uB = *reinterpret_cast<const h8v*>(ua + 64 + jj);
            da = fdot2(__builtin_shufflevector(zA, zA, 0, 1),
                       __builtin_shufflevector(uA, uA, 0, 1), da);
            da = fdot2(__builtin_shufflevector(zA, zA, 2, 3),
                       __builtin_shufflevector(uA, uA, 2, 3), da);
            da = fdot2(__builtin_shufflevector(zA, zA, 4, 5),
                       __builtin_shufflevector(uA, uA, 4, 5), da);
            da = fdot2(__builtin_shufflevector(zA, zA, 6, 7),
                       __builtin_shufflevector(uA, uA, 6, 7), da);
            db = fdot2(__builtin_shufflevector(zB, zB, 0, 1),
                       __builtin_shufflevector(uB, uB, 0, 1), db);
            db = fdot2(__builtin_shufflevector(zB, zB, 2, 3),
                       __builtin_shufflevector(uB, uB, 2, 3), db);
            db = fdot2(__builtin_shufflevector(zB, zB, 4, 5),
                       __builtin_shufflevector(uB, uB, 4, 5), db);
            db = fdot2(__builtin_shufflevector(zB, zB, 6, 7),
                       __builtin_shufflevector(uB, uB, 6, 7), db);
        }
        // softmax over 8 k (4 threads x 2 vals)
        float mx = fmaxf(da, db);
        mx = fmaxf(mx, __shfl_xor(mx, 1));
        mx = fmaxf(mx, __shfl_xor(mx, 2));
        const float ea = __expf(da - mx), eb = __expf(db - mx);
        float sm_ = ea + eb;
        sm_ += __shfl_xor(sm_, 1);
        sm_ += __shfl_xor(sm_, 2);
        const float rs = 1.0f / sm_;
        *reinterpret_cast<float2*>(p_ + dm * 8 + ka) = make_float2(ea * rs, eb * rs);
        __syncthreads();

        // u = s + sum_m z[m]*p[m, go]
        float a0 = 0, a1 = 0, a2 = 0, a3 = 0;
        for (int m = 0; m < 32; ++m) {
            const h4v z = *reinterpret_cast<const h4v*>(zr + m * D_DIM + e);
            const float pm = p_[m * 8 + go];
            a0 = fmaf((float)z[0], pm, a0); a1 = fmaf((float)z[1], pm, a1);
            a2 = fmaf((float)z[2], pm, a2); a3 = fmaf((float)z[3], pm, a3);
        }
        v0 = s0 + a0; v1 = s1 + a1; v2 = s2 + a2; v3 = s3 + a3;
        // next p_ write is after next norm's barrier -> safe
    }

    *reinterpret_cast<float4*>(out + site * D_DIM + e) =
        make_float4(fmaxf(v0, 0.0f), fmaxf(v1, 0.0f),
                    fmaxf(v2, 0.0f), fmaxf(v3, 0.0f));
}

extern "C" void kernel_launch(void* const* d_in, const int* in_sizes, int n_in,
                              void* d_out, int out_size, void* d_ws, size_t ws_size,
                              hipStream_t stream) {
    const float* self_v  = (const float*)d_in[0];   // [6400,512]
    const float* neigh_v = (const float*)d_in[1];   // [204800,512]
    const float* W1      = (const float*)d_in[2];   // [512,512]
    const float* b1      = (const float*)d_in[3];   // [512]
    const int*   miter   = (const int*)d_in[4];
    float* out = (float*)d_out;

    const int sites = in_sizes[0] / D_DIM;          // 6400
    const int nrows = in_sizes[1] / D_DIM;          // 204800

    fp16_t* s = (fp16_t*)d_ws;                      // [sites,512] f16
    short* Wb = (short*)(s + (size_t)sites * D_DIM);// [512,512] bf16

    wconv<<<dim3(D_DIM * D_DIM / (256 * 8)), dim3(256), 0, stream>>>(W1, Wb);
    gemm_route<false><<<dim3(sites / BM), dim3(512), 0, stream>>>(
        self_v, Wb, b1, s, nullptr, nullptr, nullptr);
    gemm_route<true><<<dim3(nrows / BM), dim3(512), 0, stream>>>(
        neigh_v, Wb, b1, nullptr, s, miter, out);
}

// Round 20
// 245.408 us; speedup vs baseline: 1.1481x; 1.1481x over previous
//
#include <hip/hip_runtime.h>
#include <hip/hip_bf16.h>

// B=128, N=50, NB=32, K=8, H=64, D=512. sites=6400, neighbor rows=204800.
// SESSION-BEST (round 17, 247.1 µs; structure reproduced 4x at 247-251 µs).
// Fused: per block, 64 neighbor rows (=2 sites) GEMM (bf16 MFMA) into LDS zbuf
// (f16), then 3 routing iterations in-block, write fp32 out. nz never hits HBM.
// Pipeline: single-type global_load_lds ledger, counted s_waitcnt vmcnt(10) +
// raw s_barrier — loads stay in flight across barriers. A fp32->bf16 at frag
// read. Routing datapath f16 + v_dot2_f32_f16.
// Known plateau: 2-barrier-per-K-step lockstep; 8-phase escape can't host the
// fused zbuf in LDS and unfused measured slower (r15).

#define D_DIM 512
#define BM 64
#define BK 32
#define KSTEPS 16

typedef __attribute__((ext_vector_type(8))) short short8;
typedef __attribute__((ext_vector_type(4))) float f32x4;
typedef _Float16 fp16_t;
typedef __attribute__((ext_vector_type(2))) _Float16 h2v;
typedef __attribute__((ext_vector_type(4))) _Float16 h4v;
typedef __attribute__((ext_vector_type(8))) _Float16 h8v;

static __device__ __forceinline__ short f2bf(float f) {
    __bf16 b = (__bf16)f;
    return __builtin_bit_cast(short, b);
}
static __device__ __forceinline__ void gload_lds16(const void* g, void* l) {
    __builtin_amdgcn_global_load_lds(
        (const __attribute__((address_space(1))) void*)g,
        (__attribute__((address_space(3))) void*)l, 16, 0, 0);
}

#if __has_builtin(__builtin_amdgcn_fdot2)
static __device__ __forceinline__ float fdot2(h2v a, h2v b, float c) {
    return __builtin_amdgcn_fdot2(a, b, c, false);
}
#else
static __device__ __forceinline__ float fdot2(h2v a, h2v b, float c) {
    return fmaf((float)a[0], (float)b[0], fmaf((float)a[1], (float)b[1], c));
}
#endif

__global__ __launch_bounds__(256) void wconv(const float* __restrict__ W,
                                             short* __restrict__ Wb) {
    const int i = (blockIdx.x * 256 + threadIdx.x) * 8;
    const float4 v0 = *reinterpret_cast<const float4*>(W + i);
    const float4 v1 = *reinterpret_cast<const float4*>(W + i + 4);
    short8 o;
    o[0] = f2bf(v0.x); o[1] = f2bf(v0.y); o[2] = f2bf(v0.z); o[3] = f2bf(v0.w);
    o[4] = f2bf(v1.x); o[5] = f2bf(v1.y); o[6] = f2bf(v1.z); o[7] = f2bf(v1.w);
    *reinterpret_cast<short8*>(Wb + i) = o;
}

// 256 threads = 4 waves; wave w -> 64 rows x cols [128w,128w+128).
// lAf32[2]: [64][32] f32 (8 KB each) via DMA; lB[2]: [512][32] bf16 (32 KB each).
template <bool FUSED>
__global__ __launch_bounds__(256, 2) void gemm_route(
    const float* __restrict__ A,     // [R,512] fp32
    const short* __restrict__ Wb,    // [512,512] bf16
    const float* __restrict__ bias,  // [512]
    fp16_t* __restrict__ Zs,         // !FUSED: s output f16
    const fp16_t* __restrict__ S,    // FUSED: s input f16
    const int* __restrict__ miter_ptr,
    float* __restrict__ out)         // FUSED: [sites,512] fp32
{
    __shared__ __align__(16) char smem[81920];
    float* const lAf32 = (float*)smem;           // [2][2048] f32  (16 KB)
    short* const lB = (short*)(smem + 16384);    // [2][16384] bf16 (64 KB)

    const int t = threadIdx.x;
    const int lane = t & 63;
    const int wid = t >> 6;
    const size_t row0 = (size_t)blockIdx.x * BM;
    const int wc = wid * 128;

    const int cb = wc + (lane & 15);
    float bcol[8];
    #pragma unroll
    for (int n = 0; n < 8; ++n) bcol[n] = bias[cb + n * 16];
    int miter = 0;
    if (FUSED) miter = *miter_ptr;

    // 10 DMAs per wave per step: 8 B-chunks + 2 A-chunks (1024 B each).
    auto stage = [&](int step, int buf) {
        const int k0 = (step < KSTEPS ? step : 0) * BK;
        #pragma unroll
        for (int i = 0; i < 8; ++i) {            // B: chunk = 16 rows x 64 B
            const int c = wid * 8 + i;
            const int r = c * 16 + (lane >> 2);
            const int g = ((lane & 3) - (r >> 1)) & 3;
            gload_lds16(Wb + (size_t)r * D_DIM + k0 + g * 8,
                        lB + buf * 16384 + c * 512);
        }
        #pragma unroll
        for (int i = 0; i < 2; ++i) {            // A: chunk = 8 rows x 128 B
            const int c = wid * 2 + i;
            const int r = c * 8 + (lane >> 3);
            const int g = ((lane & 7) - 2 * (r & 3)) & 7;
            gload_lds16(A + (row0 + r) * D_DIM + k0 + g * 4,
                        lAf32 + buf * 2048 + c * 256);
        }
    };

    f32x4 acc[4][8] = {};
    auto compute = [&](int buf) {
        const int q = lane >> 4;                 // k 16B-slot pair index
        short8 af[4], bfr[8];
        #pragma unroll
        for (int m = 0; m < 4; ++m) {
            const int r = m * 16 + (lane & 15);
            const float* ap = lAf32 + buf * 2048 + r * 32 + ((q + (r & 3)) & 3) * 8;
            const f32x4 a0 = *reinterpret_cast<const f32x4*>(ap);
            const f32x4 a1 = *reinterpret_cast<const f32x4*>(ap + 4);
            short8 f;
            f[0] = f2bf(a0[0]); f[1] = f2bf(a0[1]);
            f[2] = f2bf(a0[2]); f[3] = f2bf(a0[3]);
            f[4] = f2bf(a1[0]); f[5] = f2bf(a1[1]);
            f[6] = f2bf(a1[2]); f[7] = f2bf(a1[3]);
            af[m] = f;
        }
        #pragma unroll
        for (int n = 0; n < 8; ++n) {
            const int r = wc + n * 16 + (lane & 15);
            bfr[n] = *reinterpret_cast<const short8*>(
                lB + buf * 16384 + r * 32 + ((q + (r >> 1)) & 3) * 8);
        }
        #pragma unroll
        for (int m = 0; m < 4; ++m)
            #pragma unroll
            for (int n = 0; n < 8; ++n)
                acc[m][n] = __builtin_amdgcn_mfma_f32_16x16x32_bf16(
                    af[m], bfr[n], acc[m][n], 0, 0, 0);
    };

    // ---- pipeline: counted vmcnt, single op type, loads fly across barriers
    stage(0, 0);
    stage(1, 1);
    asm volatile("s_waitcnt vmcnt(10)" ::: "memory");   // stage0 (+scalars) done
    __builtin_amdgcn_s_barrier();
    #pragma unroll
    for (int tk = 0; tk < KSTEPS; ++tk) {
        compute(tk & 1);
        asm volatile("s_waitcnt lgkmcnt(0)" ::: "memory");  // reads consumed
        __builtin_amdgcn_s_barrier();                       // buf tk&1 free
        stage(tk + 2, tk & 1);                              // overwrite it
        asm volatile("s_waitcnt vmcnt(10)" ::: "memory");   // stage(tk+1) done
        __builtin_amdgcn_s_barrier();                       // visible to all
    }
    asm volatile("s_waitcnt vmcnt(0)" ::: "memory");        // drain tail junk
    __builtin_amdgcn_s_barrier();

    // ---- epilogue: bias + ReLU + l2norm per 64-col group; z as f16.
    fp16_t* const zbuf = (fp16_t*)(smem + 16384);   // aliases lB (free now)
    #pragma unroll
    for (int m = 0; m < 4; ++m) {
        #pragma unroll
        for (int r = 0; r < 4; ++r) {
            float v[8];
            float ssa = 0.0f, ssb = 0.0f;
            #pragma unroll
            for (int n = 0; n < 4; ++n) {
                v[n] = fmaxf(acc[m][n][r] + bcol[n], 0.0f);
                ssa = fmaf(v[n], v[n], ssa);
            }
            #pragma unroll
            for (int n = 4; n < 8; ++n) {
                v[n] = fmaxf(acc[m][n][r] + bcol[n], 0.0f);
                ssb = fmaf(v[n], v[n], ssb);
            }
            ssa += __shfl_xor(ssa, 1); ssb += __shfl_xor(ssb, 1);
            ssa += __shfl_xor(ssa, 2); ssb += __shfl_xor(ssb, 2);
            ssa += __shfl_xor(ssa, 4); ssb += __shfl_xor(ssb, 4);
            ssa += __shfl_xor(ssa, 8); ssb += __shfl_xor(ssb, 8);
            const float inva = 1.0f / fmaxf(sqrtf(ssa), 1e-12f);
            const float invb = 1.0f / fmaxf(sqrtf(ssb), 1e-12f);
            const int orow = m * 16 + (lane >> 4) * 4 + r;   // 0..63
            if (FUSED) {
                #pragma unroll
                for (int n = 0; n < 4; ++n)
                    zbuf[orow * D_DIM + cb + n * 16] = (fp16_t)(v[n] * inva);
                #pragma unroll
                for (int n = 4; n < 8; ++n)
                    zbuf[orow * D_DIM + cb + n * 16] = (fp16_t)(v[n] * invb);
            } else {
                #pragma unroll
                for (int n = 0; n < 4; ++n)
                    Zs[(row0 + orow) * D_DIM + cb + n * 16] = (fp16_t)(v[n] * inva);
                #pragma unroll
                for (int n = 4; n < 8; ++n)
                    Zs[(row0 + orow) * D_DIM + cb + n * 16] = (fp16_t)(v[n] * invb);
            }
        }
    }

    if (!FUSED) return;
    __syncthreads();   // zbuf complete

    // ---- routing: 2 sites/block, 128 threads each; f16 z/u + fdot2 dots.
    fp16_t* const uh = (fp16_t*)smem;               // [2][512] f16 (aliases lAf32)
    float* const ppb = (float*)(smem + 4096);       // [2][256] f32
    const int tt = t & 127;
    const int ssid = t >> 7;
    const size_t site = (size_t)blockIdx.x * 2 + ssid;
    fp16_t* const u_ = uh + ssid * D_DIM;
    float* const p_ = ppb + ssid * 256;
    const fp16_t* const zr = zbuf + ssid * 32 * D_DIM;

    const int e = tt * 4;
    const int go = tt >> 4;                  // capsule group of owned elems
    const h4v sv = *reinterpret_cast<const h4v*>(S + site * D_DIM + e);
    const float s0 = (float)sv[0], s1 = (float)sv[1];
    const float s2 = (float)sv[2], s3 = (float)sv[3];

    float v0, v1, v2, v3;
    {   // iteration 0: p uniform 1/8
        float a0 = 0, a1 = 0, a2 = 0, a3 = 0;
        for (int m = 0; m < 32; ++m) {
            const h4v z = *reinterpret_cast<const h4v*>(zr + m * D_DIM + e);
            a0 += (float)z[0]; a1 += (float)z[1];
            a2 += (float)z[2]; a3 += (float)z[3];
        }
        v0 = fmaf(a0, 0.125f, s0); v1 = fmaf(a1, 0.125f, s1);
        v2 = fmaf(a2, 0.125f, s2); v3 = fmaf(a3, 0.125f, s3);
    }

    const int dm = tt >> 2;                  // neighbor for this thread's dots
    const int ka = (tt & 3) * 2;             // capsule pair
    const fp16_t* const za = zr + dm * D_DIM + ka * 64;
    const fp16_t* const ua = u_ + ka * 64;

    for (int it = 1; it < miter; ++it) {
        // normalize u per 64-group (16-thread shfl groups, wave-aligned)
        float ssum = v0 * v0 + v1 * v1 + v2 * v2 + v3 * v3;
        ssum += __shfl_xor(ssum, 1);
        ssum += __shfl_xor(ssum, 2);
        ssum += __shfl_xor(ssum, 4);
        ssum += __shfl_xor(ssum, 8);
        const float inv = 1.0f / fmaxf(sqrtf(ssum), 1e-12f);
        v0 *= inv; v1 *= inv; v2 *= inv; v3 *= inv;
        h4v uw; uw[0] = (fp16_t)v0; uw[1] = (fp16_t)v1;
        uw[2] = (fp16_t)v2; uw[3] = (fp16_t)v3;
        *reinterpret_cast<h4v*>(u_ + e) = uw;
        __syncthreads();

        // dots p[dm][ka], p[dm][ka+1] via v_dot2_f32_f16; staggered octets
        float da = 0.0f, db = 0.0f;
        #pragma unroll
        for (int j = 0; j < 8; ++j) {
            const int jj = ((j + (tt & 7)) & 7) * 8;
            const h8v zA = *reinterpret_cast<const h8v*>(za + jj);
            const h8v uA = *reinterpret_cast<const h8v*>(ua + jj);
            const h8v zB = *reinterpret_cast<const h8v*>(za + 64 + jj);
            const h8v uB = *reinterpret_cast<const h8v*>(ua + 64 + jj);
            da = fdot2(__builtin_shufflevector(zA, zA, 0, 1),
                       __builtin_shufflevector(uA, uA, 0, 1), da);
            da = fdot2(__builtin_shufflevector(zA, zA, 2, 3),
                       __builtin_shufflevector(uA, uA, 2, 3), da);
            da = fdot2(__builtin_shufflevector(zA, zA, 4, 5),
                       __builtin_shufflevector(uA, uA, 4, 5), da);
            da = fdot2(__builtin_shufflevector(zA, zA, 6, 7),
                       __builtin_shufflevector(uA, uA, 6, 7), da);
            db = fdot2(__builtin_shufflevector(zB, zB, 0, 1),
                       __builtin_shufflevector(uB, uB, 0, 1), db);
            db = fdot2(__builtin_shufflevector(zB, zB, 2, 3),
                       __builtin_shufflevector(uB, uB, 2, 3), db);
            db = fdot2(__builtin_shufflevector(zB, zB, 4, 5),
                       __builtin_shufflevector(uB, uB, 4, 5), db);
            db = fdot2(__builtin_shufflevector(zB, zB, 6, 7),
                       __builtin_shufflevector(uB, uB, 6, 7), db);
        }
        // softmax over 8 k (4 threads x 2 vals)
        float mx = fmaxf(da, db);
        mx = fmaxf(mx, __shfl_xor(mx, 1));
        mx = fmaxf(mx, __shfl_xor(mx, 2));
        const float ea = __expf(da - mx), eb = __expf(db - mx);
        float sm_ = ea + eb;
        sm_ += __shfl_xor(sm_, 1);
        sm_ += __shfl_xor(sm_, 2);
        const float rs = 1.0f / sm_;
        *reinterpret_cast<float2*>(p_ + dm * 8 + ka) = make_float2(ea * rs, eb * rs);
        __syncthreads();

        // u = s + sum_m z[m]*p[m, go]
        float a0 = 0, a1 = 0, a2 = 0, a3 = 0;
        for (int m = 0; m < 32; ++m) {
            const h4v z = *reinterpret_cast<const h4v*>(zr + m * D_DIM + e);
            const float pm = p_[m * 8 + go];
            a0 = fmaf((float)z[0], pm, a0); a1 = fmaf((float)z[1], pm, a1);
            a2 = fmaf((float)z[2], pm, a2); a3 = fmaf((float)z[3], pm, a3);
        }
        v0 = s0 + a0; v1 = s1 + a1; v2 = s2 + a2; v3 = s3 + a3;
        // next p_ write is after next norm's barrier -> safe
    }

    *reinterpret_cast<float4*>(out + site * D_DIM + e) =
        make_float4(fmaxf(v0, 0.0f), fmaxf(v1, 0.0f),
                    fmaxf(v2, 0.0f), fmaxf(v3, 0.0f));
}

extern "C" void kernel_launch(void* const* d_in, const int* in_sizes, int n_in,
                              void* d_out, int out_size, void* d_ws, size_t ws_size,
                              hipStream_t stream) {
    const float* self_v  = (const float*)d_in[0];   // [6400,512]
    const float* neigh_v = (const float*)d_in[1];   // [204800,512]
    const float* W1      = (const float*)d_in[2];   // [512,512]
    const float* b1      = (const float*)d_in[3];   // [512]
    const int*   miter   = (const int*)d_in[4];
    float* out = (float*)d_out;

    const int sites = in_sizes[0] / D_DIM;          // 6400
    const int nrows = in_sizes[1] / D_DIM;          // 204800

    fp16_t* s = (fp16_t*)d_ws;                      // [sites,512] f16
    short* Wb = (short*)(s + (size_t)sites * D_DIM);// [512,512] bf16

    wconv<<<dim3(D_DIM * D_DIM / (256 * 8)), dim3(256), 0, stream>>>(W1, Wb);
    gemm_route<false><<<dim3(sites / BM), dim3(256), 0, stream>>>(
        self_v, Wb, b1, s, nullptr, nullptr, nullptr);
    gemm_route<true><<<dim3(nrows / BM), dim3(256), 0, stream>>>(
        neigh_v, Wb, b1, nullptr, s, miter, out);
}